// Round 1
// baseline (542.783 us; speedup 1.0000x reference)
//
#include <hip/hip_runtime.h>
#include <math.h>

#define B_TOT   1024
#define L_SEQ   200
#define DIM     64
#define VOCAB   100001
#define NEG_BIG (-1e15f)
#define NV_CHUNKS 256
#define VSTAGE  64

// ---------------------------------------------------------------------------
// Kernel A: attention pooling.  One block (64 threads = 1 wave) per batch row.
// Q[b][d] = sum_l attn[l] * mask[l] * (8*item_emb[id_l][d] + pos_emb[l][d])
// ---------------------------------------------------------------------------
__global__ __launch_bounds__(64) void pool_kernel(
    const int*   __restrict__ log_seqs,
    const float* __restrict__ item_emb,
    const float* __restrict__ attn_key,
    const float* __restrict__ pos_emb,
    float*       __restrict__ Q)
{
    const int b = blockIdx.x;
    const int t = threadIdx.x;            // 0..63

    __shared__ float s_posdot[L_SEQ];
    __shared__ float s_sim[L_SEQ];
    __shared__ float s_attn[L_SEQ];
    __shared__ int   s_ids[L_SEQ];

    // key -> registers (all 64 values per thread)
    float key[DIM];
    #pragma unroll
    for (int i = 0; i < DIM / 4; ++i) {
        const float4 k4 = ((const float4*)attn_key)[i];
        key[4*i+0] = k4.x; key[4*i+1] = k4.y;
        key[4*i+2] = k4.z; key[4*i+3] = k4.w;
    }

    // posdot[l] = dot(pos_emb[l], key)
    for (int l = t; l < L_SEQ; l += 64) {
        float acc = 0.f;
        #pragma unroll
        for (int i = 0; i < DIM / 4; ++i) {
            const float4 p = ((const float4*)(pos_emb + l * DIM))[i];
            acc += p.x*key[4*i] + p.y*key[4*i+1] + p.z*key[4*i+2] + p.w*key[4*i+3];
        }
        s_posdot[l] = acc;
    }
    __syncthreads();

    // sim[l]
    const int* seq_row = log_seqs + (long)b * L_SEQ;
    for (int l = t; l < L_SEQ; l += 64) {
        const int id = seq_row[l];
        s_ids[l] = id;
        float sim;
        if (id == 0) {
            sim = NEG_BIG;                 // seqs row zeroed -> dot 0, + NEG
        } else {
            float acc = 0.f;
            const float4* e4 = (const float4*)(item_emb + (long)id * DIM);
            #pragma unroll
            for (int i = 0; i < DIM / 4; ++i) {
                const float4 e = e4[i];
                acc += e.x*key[4*i] + e.y*key[4*i+1] + e.z*key[4*i+2] + e.w*key[4*i+3];
            }
            sim = 8.0f * acc + s_posdot[l];
        }
        s_sim[l] = sim;
    }
    __syncthreads();

    // softmax over L (single wave: shfl reductions)
    float lm = -INFINITY;
    for (int l = t; l < L_SEQ; l += 64) lm = fmaxf(lm, s_sim[l]);
    #pragma unroll
    for (int off = 32; off > 0; off >>= 1) lm = fmaxf(lm, __shfl_xor(lm, off));

    float ls = 0.f;
    for (int l = t; l < L_SEQ; l += 64) {
        const float p = __expf(s_sim[l] - lm);
        s_attn[l] = p;
        ls += p;
    }
    #pragma unroll
    for (int off = 32; off > 0; off >>= 1) ls += __shfl_xor(ls, off);
    const float inv = 1.0f / ls;
    __syncthreads();

    // Q[b][d], d = t  (coalesced item_emb reads across the wave)
    float q = 0.f;
    for (int l = 0; l < L_SEQ; ++l) {
        const int   id = s_ids[l];
        const float a  = s_attn[l] * inv;
        const float e  = item_emb[(long)id * DIM + t];
        const float p  = pos_emb[l * DIM + t];
        const float seq = (id != 0) ? fmaf(8.0f, e, p) : 0.0f;
        q = fmaf(a, seq, q);
    }
    Q[b * DIM + t] = q;
}

// ---------------------------------------------------------------------------
// Kernel B: fused logits GEMM + online softmax partials.
// Grid: NV_CHUNKS blocks x 1024 threads. Thread tid owns batch row b = tid
// (Q row in 64 VGPRs). Block owns one vocab chunk; E rows staged in LDS,
// read broadcast (uniform address across the wave -> no bank conflicts).
// Emits per-(chunk,b) partial (max, sum_exp).
// ---------------------------------------------------------------------------
__global__ __launch_bounds__(1024) void logits_kernel(
    const float* __restrict__ Q,
    const float* __restrict__ item_emb,
    float*       __restrict__ partials)   // [NV_CHUNKS][B][2]
{
    const int chunk = blockIdx.x;
    const int tid   = threadIdx.x;        // == b
    const int b     = tid;

    __shared__ float sE[VSTAGE][DIM];

    const int per = (VOCAB + NV_CHUNKS - 1) / NV_CHUNKS;   // 391
    const int c0  = chunk * per;
    const int c1  = min(c0 + per, VOCAB);

    float q[DIM];
    #pragma unroll
    for (int i = 0; i < DIM / 4; ++i) {
        const float4 v = ((const float4*)(Q + b * DIM))[i];
        q[4*i+0] = v.x; q[4*i+1] = v.y; q[4*i+2] = v.z; q[4*i+3] = v.w;
    }

    float m = -INFINITY, s = 0.f;

    for (int v0 = c0; v0 < c1; v0 += VSTAGE) {
        __syncthreads();
        // cooperative stage: 64 rows x 64 floats = 1024 float4, 1 per thread
        {
            const int row = tid >> 4;
            const int col = tid & 15;
            const int v   = v0 + row;
            float4 val = make_float4(0.f, 0.f, 0.f, 0.f);
            if (v < c1) val = ((const float4*)(item_emb + (long)v * DIM))[col];
            ((float4*)(&sE[row][0]))[col] = val;
        }
        __syncthreads();

        const int nv = min(VSTAGE, c1 - v0);
        for (int j = 0; j < nv; ++j) {
            float acc = 0.f;
            const float4* e4 = (const float4*)(&sE[j][0]);
            #pragma unroll
            for (int i = 0; i < DIM / 4; ++i) {
                const float4 e = e4[i];
                acc += e.x*q[4*i] + e.y*q[4*i+1] + e.z*q[4*i+2] + e.w*q[4*i+3];
            }
            const float mn = fmaxf(m, acc);
            s = s * __expf(m - mn) + __expf(acc - mn);
            m = mn;
        }
    }

    float2* p2 = (float2*)(partials + (size_t)(chunk * B_TOT + b) * 2);
    *p2 = make_float2(m, s);
}

// ---------------------------------------------------------------------------
// Kernel C: reduce partials, gather pred logit, emit prob.
// ---------------------------------------------------------------------------
__global__ __launch_bounds__(256) void finalize_kernel(
    const float* __restrict__ Q,
    const float* __restrict__ item_emb,
    const int*   __restrict__ pred,
    const float* __restrict__ partials,
    float*       __restrict__ out)
{
    const int b = blockIdx.x * 256 + threadIdx.x;

    float M = -INFINITY;
    for (int c = 0; c < NV_CHUNKS; ++c) {
        const float2 p = ((const float2*)partials)[c * B_TOT + b];
        M = fmaxf(M, p.x);
    }
    float S = 0.f;
    for (int c = 0; c < NV_CHUNKS; ++c) {
        const float2 p = ((const float2*)partials)[c * B_TOT + b];
        S += p.y * __expf(p.x - M);
    }

    const int pv = pred[b];
    float acc = 0.f;
    const float4* e4 = (const float4*)(item_emb + (long)pv * DIM);
    const float4* q4 = (const float4*)(Q + b * DIM);
    #pragma unroll
    for (int i = 0; i < DIM / 4; ++i) {
        const float4 e = e4[i];
        const float qv = 0.f; (void)qv;
        const float4 qq = q4[i];
        acc += e.x*qq.x + e.y*qq.y + e.z*qq.z + e.w*qq.w;
    }
    out[b] = __expf(acc - M) / S;
}

// ---------------------------------------------------------------------------
extern "C" void kernel_launch(void* const* d_in, const int* in_sizes, int n_in,
                              void* d_out, int out_size, void* d_ws, size_t ws_size,
                              hipStream_t stream)
{
    const int*   log_seqs = (const int*)  d_in[0];
    const int*   pred     = (const int*)  d_in[1];
    const float* item_emb = (const float*)d_in[2];
    const float* attn_key = (const float*)d_in[3];
    const float* pos_emb  = (const float*)d_in[4];
    float*       out      = (float*)d_out;

    float* Q        = (float*)d_ws;                    // [B][64]
    float* partials = Q + (size_t)B_TOT * DIM;         // [NV][B][2]

    pool_kernel<<<B_TOT, 64, 0, stream>>>(log_seqs, item_emb, attn_key, pos_emb, Q);
    logits_kernel<<<NV_CHUNKS, 1024, 0, stream>>>(Q, item_emb, partials);
    finalize_kernel<<<B_TOT / 256, 256, 0, stream>>>(Q, item_emb, pred, partials, out);
}

// Round 2
// 134.681 us; speedup vs baseline: 4.0301x; 4.0301x over previous
//
#include <hip/hip_runtime.h>
#include <math.h>

#define B_TOT   1024
#define L_SEQ   200
#define DIM     64
#define VOCAB   100001
#define NEG_BIG (-1e15f)

typedef __bf16 bf16x8 __attribute__((ext_vector_type(8)));
typedef float  f32x4  __attribute__((ext_vector_type(4)));

// ---------------------------------------------------------------------------
// Kernel 0: convert item_emb fp32 -> bf16 (row-major [VOCAB][64])
// ---------------------------------------------------------------------------
__global__ __launch_bounds__(256) void convert_kernel(
    const float* __restrict__ src,
    __bf16*      __restrict__ dst)
{
    const long n = (long)VOCAB * DIM;            // 6,400,064 = 8 * 800,008
    const long i = ((long)blockIdx.x * 256 + threadIdx.x) * 8;
    if (i + 8 > n) return;
    const float4 f0 = ((const float4*)(src + i))[0];
    const float4 f1 = ((const float4*)(src + i))[1];
    bf16x8 o;
    o[0] = (__bf16)f0.x; o[1] = (__bf16)f0.y; o[2] = (__bf16)f0.z; o[3] = (__bf16)f0.w;
    o[4] = (__bf16)f1.x; o[5] = (__bf16)f1.y; o[6] = (__bf16)f1.z; o[7] = (__bf16)f1.w;
    *(bf16x8*)(dst + i) = o;
}

// ---------------------------------------------------------------------------
// Kernel A: attention pooling. One wave per batch row.
// Writes Q fp32 (for exact pred-logit) and Q bf16 (MFMA A operand).
// ---------------------------------------------------------------------------
__global__ __launch_bounds__(64) void pool_kernel(
    const int*   __restrict__ log_seqs,
    const float* __restrict__ item_emb,
    const float* __restrict__ attn_key,
    const float* __restrict__ pos_emb,
    float*       __restrict__ Q,
    __bf16*      __restrict__ Qb)
{
    const int b = blockIdx.x;
    const int t = threadIdx.x;            // 0..63

    __shared__ float s_posdot[L_SEQ];
    __shared__ float s_sim[L_SEQ];
    __shared__ float s_attn[L_SEQ];
    __shared__ int   s_ids[L_SEQ];

    float key[DIM];
    #pragma unroll
    for (int i = 0; i < DIM / 4; ++i) {
        const float4 k4 = ((const float4*)attn_key)[i];
        key[4*i+0] = k4.x; key[4*i+1] = k4.y;
        key[4*i+2] = k4.z; key[4*i+3] = k4.w;
    }

    for (int l = t; l < L_SEQ; l += 64) {
        float acc = 0.f;
        #pragma unroll
        for (int i = 0; i < DIM / 4; ++i) {
            const float4 p = ((const float4*)(pos_emb + l * DIM))[i];
            acc += p.x*key[4*i] + p.y*key[4*i+1] + p.z*key[4*i+2] + p.w*key[4*i+3];
        }
        s_posdot[l] = acc;
    }
    __syncthreads();

    const int* seq_row = log_seqs + (long)b * L_SEQ;
    for (int l = t; l < L_SEQ; l += 64) {
        const int id = seq_row[l];
        s_ids[l] = id;
        float sim;
        if (id == 0) {
            sim = NEG_BIG;
        } else {
            float acc = 0.f;
            const float4* e4 = (const float4*)(item_emb + (long)id * DIM);
            #pragma unroll
            for (int i = 0; i < DIM / 4; ++i) {
                const float4 e = e4[i];
                acc += e.x*key[4*i] + e.y*key[4*i+1] + e.z*key[4*i+2] + e.w*key[4*i+3];
            }
            sim = 8.0f * acc + s_posdot[l];
        }
        s_sim[l] = sim;
    }
    __syncthreads();

    float lm = -INFINITY;
    for (int l = t; l < L_SEQ; l += 64) lm = fmaxf(lm, s_sim[l]);
    #pragma unroll
    for (int off = 32; off > 0; off >>= 1) lm = fmaxf(lm, __shfl_xor(lm, off));

    float ls = 0.f;
    for (int l = t; l < L_SEQ; l += 64) {
        const float p = __expf(s_sim[l] - lm);
        s_attn[l] = p;
        ls += p;
    }
    #pragma unroll
    for (int off = 32; off > 0; off >>= 1) ls += __shfl_xor(ls, off);
    const float inv = 1.0f / ls;
    __syncthreads();

    float q = 0.f;
    for (int l = 0; l < L_SEQ; ++l) {
        const int   id = s_ids[l];
        const float a  = s_attn[l] * inv;
        const float e  = item_emb[(long)id * DIM + t];
        const float p  = pos_emb[l * DIM + t];
        const float seq = (id != 0) ? fmaf(8.0f, e, p) : 0.0f;
        q = fmaf(a, seq, q);
    }
    Q[b * DIM + t]  = q;
    Qb[b * DIM + t] = (__bf16)q;
}

// ---------------------------------------------------------------------------
// Kernel B: bf16 MFMA logits GEMM + exp-sum partials (no max needed: logits
// are bounded, exp-safe; mathematically identical to max-subtracted softmax).
//
// Block = 256 threads = 4 waves; block owns 64 batch rows (4 b-tiles) and one
// vocab chunk; waves split the chunk's 16-row v-tiles round-robin.
// A-frag: lane holds Q[btile*16 + (lane&15)][kslice*32 + (lane>>4)*8 .. +7]
// B-frag: lane holds E[vtile*16 + (lane&15)][same k range]   (C = Q . E^T)
// C/D:    col = lane&15 (vocab), row = (lane>>4)*4 + reg (batch)  [m89 layout]
// ---------------------------------------------------------------------------
#define NC        64                    // vocab chunks
#define NBG       16                    // batch groups (1024/64)
#define VT_TOTAL  6251                  // ceil(100001/16)
#define VT_FULL   6250

__global__ __launch_bounds__(256) void logits_mfma(
    const __bf16* __restrict__ Eb,      // [VOCAB][64]
    const __bf16* __restrict__ Qb,      // [1024][64]
    float*        __restrict__ partials) // [NC*4][1024]
{
    const int bg    = blockIdx.x / NC;
    const int chunk = blockIdx.x % NC;
    const int wave  = threadIdx.x >> 6;
    const int lane  = threadIdx.x & 63;
    const int r16   = lane & 15;
    const int hi    = lane >> 4;

    bf16x8 a[4][2];
    #pragma unroll
    for (int t = 0; t < 4; ++t)
        #pragma unroll
        for (int s = 0; s < 2; ++s)
            a[t][s] = *(const bf16x8*)(Qb + ((bg*64 + t*16 + r16) * DIM) + s*32 + hi*8);

    const int per    = (VT_TOTAL + NC - 1) / NC;   // 98
    const int vt_end = min((chunk + 1) * per, VT_TOTAL);
    int vt = chunk * per + wave;

    float ssum[4][4];
    #pragma unroll
    for (int t = 0; t < 4; ++t)
        #pragma unroll
        for (int r = 0; r < 4; ++r) ssum[t][r] = 0.f;

    // register double-buffered B-fragment stream
    bf16x8 b0, b1;
    if (vt < vt_end) {
        const int row = min(vt * 16 + r16, VOCAB - 1);
        const __bf16* p = Eb + (size_t)row * DIM + hi * 8;
        b0 = *(const bf16x8*)p;
        b1 = *(const bf16x8*)(p + 32);
    }
    while (vt < vt_end) {
        const bf16x8 c0 = b0, c1 = b1;
        const int vt_cur = vt;
        vt += 4;
        if (vt < vt_end) {
            const int row = min(vt * 16 + r16, VOCAB - 1);
            const __bf16* p = Eb + (size_t)row * DIM + hi * 8;
            b0 = *(const bf16x8*)p;
            b1 = *(const bf16x8*)(p + 32);
        }
        if (vt_cur < VT_FULL) {
            #pragma unroll
            for (int t = 0; t < 4; ++t) {
                f32x4 acc = {0.f, 0.f, 0.f, 0.f};
                acc = __builtin_amdgcn_mfma_f32_16x16x32_bf16(a[t][0], c0, acc, 0, 0, 0);
                acc = __builtin_amdgcn_mfma_f32_16x16x32_bf16(a[t][1], c1, acc, 0, 0, 0);
                #pragma unroll
                for (int r = 0; r < 4; ++r) ssum[t][r] += __expf(acc[r]);
            }
        } else {
            // tail tile: only col 0 is a real vocab row (VOCAB % 16 == 1)
            const bool valid = (vt_cur * 16 + r16) < VOCAB;
            #pragma unroll
            for (int t = 0; t < 4; ++t) {
                f32x4 acc = {0.f, 0.f, 0.f, 0.f};
                acc = __builtin_amdgcn_mfma_f32_16x16x32_bf16(a[t][0], c0, acc, 0, 0, 0);
                acc = __builtin_amdgcn_mfma_f32_16x16x32_bf16(a[t][1], c1, acc, 0, 0, 0);
                #pragma unroll
                for (int r = 0; r < 4; ++r) ssum[t][r] += valid ? __expf(acc[r]) : 0.f;
            }
        }
    }

    // reduce exp-sums across the 16 vocab cols (lanes differing in bits 0..3)
    #pragma unroll
    for (int t = 0; t < 4; ++t)
        #pragma unroll
        for (int r = 0; r < 4; ++r) {
            float v = ssum[t][r];
            v += __shfl_xor(v, 1);
            v += __shfl_xor(v, 2);
            v += __shfl_xor(v, 4);
            v += __shfl_xor(v, 8);
            ssum[t][r] = v;
        }

    if (r16 == 0) {
        const int wslot = chunk * 4 + wave;
        #pragma unroll
        for (int t = 0; t < 4; ++t)
            #pragma unroll
            for (int r = 0; r < 4; ++r) {
                const int row = bg * 64 + t * 16 + hi * 4 + r;
                partials[(size_t)wslot * B_TOT + row] = ssum[t][r];
            }
    }
}

// ---------------------------------------------------------------------------
// Kernel C: reduce partials, exact fp32 pred logit, emit prob.
// ---------------------------------------------------------------------------
__global__ __launch_bounds__(256) void finalize_kernel(
    const float* __restrict__ Q,
    const float* __restrict__ item_emb,
    const int*   __restrict__ pred,
    const float* __restrict__ partials,
    float*       __restrict__ out)
{
    const int b = blockIdx.x * 256 + threadIdx.x;

    float S = 0.f;
    for (int w = 0; w < NC * 4; ++w)
        S += partials[(size_t)w * B_TOT + b];

    const int pv = pred[b];
    float acc = 0.f;
    const float4* e4 = (const float4*)(item_emb + (long)pv * DIM);
    const float4* q4 = (const float4*)(Q + b * DIM);
    #pragma unroll
    for (int i = 0; i < DIM / 4; ++i) {
        const float4 e = e4[i];
        const float4 q = q4[i];
        acc += e.x*q.x + e.y*q.y + e.z*q.z + e.w*q.w;
    }
    out[b] = __expf(acc) / S;
}

// ---------------------------------------------------------------------------
extern "C" void kernel_launch(void* const* d_in, const int* in_sizes, int n_in,
                              void* d_out, int out_size, void* d_ws, size_t ws_size,
                              hipStream_t stream)
{
    const int*   log_seqs = (const int*)  d_in[0];
    const int*   pred     = (const int*)  d_in[1];
    const float* item_emb = (const float*)d_in[2];
    const float* attn_key = (const float*)d_in[3];
    const float* pos_emb  = (const float*)d_in[4];
    float*       out      = (float*)d_out;

    char* ws = (char*)d_ws;
    __bf16* Eb       = (__bf16*)ws;                                   // 12,800,128 B
    __bf16* Qb       = (__bf16*)(ws + (size_t)VOCAB * DIM * 2);       // 131,072 B
    float*  Qf       = (float*) (ws + (size_t)VOCAB * DIM * 2 + (size_t)B_TOT * DIM * 2);
    float*  partials = (float*) ((char*)Qf + (size_t)B_TOT * DIM * 4); // [256][1024] f32

    {   // convert item_emb -> bf16
        const long n8 = ((long)VOCAB * DIM) / 8;                      // 800,008
        const int blocks = (int)((n8 + 255) / 256);
        convert_kernel<<<blocks, 256, 0, stream>>>(item_emb, Eb);
    }
    pool_kernel<<<B_TOT, 64, 0, stream>>>(log_seqs, item_emb, attn_key, pos_emb, Qf, Qb);
    logits_mfma<<<NBG * NC, 256, 0, stream>>>(Eb, Qb, partials);
    finalize_kernel<<<B_TOT / 256, 256, 0, stream>>>(Qf, item_emb, pred, partials, out);
}

// Round 3
// 90.724 us; speedup vs baseline: 5.9828x; 1.4845x over previous
//
#include <hip/hip_runtime.h>
#include <math.h>

#define B_TOT   1024
#define L_SEQ   200
#define DIM     64
#define VOCAB   100001
#define NEG_BIG (-1e15f)

typedef __bf16 bf16x8 __attribute__((ext_vector_type(8)));
typedef float  f32x4  __attribute__((ext_vector_type(4)));

// ---------------------------------------------------------------------------
// Kernel 0: convert item_emb fp32 -> bf16 (row-major [VOCAB][64])
// ---------------------------------------------------------------------------
__global__ __launch_bounds__(256) void convert_kernel(
    const float* __restrict__ src,
    __bf16*      __restrict__ dst)
{
    const long n = (long)VOCAB * DIM;            // 6,400,064 = 8 * 800,008
    const long i = ((long)blockIdx.x * 256 + threadIdx.x) * 8;
    if (i + 8 > n) return;
    const float4 f0 = ((const float4*)(src + i))[0];
    const float4 f1 = ((const float4*)(src + i))[1];
    bf16x8 o;
    o[0] = (__bf16)f0.x; o[1] = (__bf16)f0.y; o[2] = (__bf16)f0.z; o[3] = (__bf16)f0.w;
    o[4] = (__bf16)f1.x; o[5] = (__bf16)f1.y; o[6] = (__bf16)f1.z; o[7] = (__bf16)f1.w;
    *(bf16x8*)(dst + i) = o;
}

// ---------------------------------------------------------------------------
// Kernel A: attention pooling. 256 threads (4 waves) per batch row.
// Phase 1: thread l computes sim[l] (one E-row gather per thread, all in
//          flight at once).  Phase 2: block softmax.  Phase 3: Q = sum_l
//          attn[l]*seq[l][:], L split across the 4 waves (lane = d), E rows
//          re-read L2-hot, cross-wave LDS reduce.
// ---------------------------------------------------------------------------
__global__ __launch_bounds__(256) void pool_kernel(
    const int*   __restrict__ log_seqs,
    const float* __restrict__ item_emb,
    const float* __restrict__ attn_key,
    const float* __restrict__ pos_emb,
    float*       __restrict__ Q,
    __bf16*      __restrict__ Qb)
{
    const int b    = blockIdx.x;
    const int t    = threadIdx.x;
    const int wave = t >> 6;
    const int lane = t & 63;

    __shared__ float s_sim[256];
    __shared__ float s_attn[L_SEQ];
    __shared__ int   s_ids[L_SEQ];
    __shared__ float s_red[4];
    __shared__ float s_q[4][DIM];

    // ---- phase 1: sim[l], one l per thread -------------------------------
    float sim = -INFINITY;                       // padding for the reduce
    if (t < L_SEQ) {
        const int id = log_seqs[(long)b * L_SEQ + t];
        s_ids[t] = id;
        if (id == 0) {
            sim = NEG_BIG;
        } else {
            float acc = 0.f;
            const float4* e4 = (const float4*)(item_emb + (long)id * DIM);
            const float4* p4 = (const float4*)(pos_emb + t * DIM);
            #pragma unroll
            for (int i = 0; i < DIM / 4; ++i) {
                const float4 e = e4[i];
                const float4 p = p4[i];
                // attn_key reads are thread-uniform -> scalar loads
                acc += fmaf(8.f, e.x, p.x) * attn_key[4*i+0]
                     + fmaf(8.f, e.y, p.y) * attn_key[4*i+1]
                     + fmaf(8.f, e.z, p.z) * attn_key[4*i+2]
                     + fmaf(8.f, e.w, p.w) * attn_key[4*i+3];
            }
            sim = acc;
        }
    }
    s_sim[t] = sim;

    // ---- phase 2: block softmax over l ------------------------------------
    float m = sim;
    #pragma unroll
    for (int off = 32; off > 0; off >>= 1) m = fmaxf(m, __shfl_xor(m, off));
    if (lane == 0) s_red[wave] = m;
    __syncthreads();
    m = fmaxf(fmaxf(s_red[0], s_red[1]), fmaxf(s_red[2], s_red[3]));
    __syncthreads();                             // everyone read s_red

    float p = (t < L_SEQ) ? __expf(s_sim[t] - m) : 0.f;
    if (t < L_SEQ) s_attn[t] = p;
    float ls = p;
    #pragma unroll
    for (int off = 32; off > 0; off >>= 1) ls += __shfl_xor(ls, off);
    if (lane == 0) s_red[wave] = ls;
    __syncthreads();
    const float inv = 1.0f / (s_red[0] + s_red[1] + s_red[2] + s_red[3]);

    // ---- phase 3: Q accumulation, L split across waves --------------------
    float q = 0.f;
    const int l0 = wave * (L_SEQ / 4);
    const int l1 = l0 + (L_SEQ / 4);
    for (int l = l0; l < l1; ++l) {
        const int   id = s_ids[l];
        const float a  = s_attn[l] * inv;
        const float e  = item_emb[(long)id * DIM + lane];   // L2-hot (phase 1)
        const float pp = pos_emb[l * DIM + lane];
        q = fmaf(a, (id != 0) ? fmaf(8.f, e, pp) : 0.f, q);
    }
    s_q[wave][lane] = q;
    __syncthreads();

    if (t < DIM) {
        const float qq = s_q[0][t] + s_q[1][t] + s_q[2][t] + s_q[3][t];
        Q[b * DIM + t]  = qq;
        Qb[b * DIM + t] = (__bf16)qq;
    }
}

// ---------------------------------------------------------------------------
// Kernel B: bf16 MFMA logits GEMM + exp-sum partials (no max needed: logits
// are bounded, exp-safe; mathematically identical to max-subtracted softmax).
// ---------------------------------------------------------------------------
#define NC        64                    // vocab chunks
#define NBG       16                    // batch groups (1024/64)
#define VT_TOTAL  6251                  // ceil(100001/16)
#define VT_FULL   6250

__global__ __launch_bounds__(256) void logits_mfma(
    const __bf16* __restrict__ Eb,      // [VOCAB][64]
    const __bf16* __restrict__ Qb,      // [1024][64]
    float*        __restrict__ partials) // [NC*4][1024]
{
    const int bg    = blockIdx.x / NC;
    const int chunk = blockIdx.x % NC;
    const int wave  = threadIdx.x >> 6;
    const int lane  = threadIdx.x & 63;
    const int r16   = lane & 15;
    const int hi    = lane >> 4;

    bf16x8 a[4][2];
    #pragma unroll
    for (int t = 0; t < 4; ++t)
        #pragma unroll
        for (int s = 0; s < 2; ++s)
            a[t][s] = *(const bf16x8*)(Qb + ((bg*64 + t*16 + r16) * DIM) + s*32 + hi*8);

    const int per    = (VT_TOTAL + NC - 1) / NC;   // 98
    const int vt_end = min((chunk + 1) * per, VT_TOTAL);
    int vt = chunk * per + wave;

    float ssum[4][4];
    #pragma unroll
    for (int t = 0; t < 4; ++t)
        #pragma unroll
        for (int r = 0; r < 4; ++r) ssum[t][r] = 0.f;

    bf16x8 b0, b1;
    if (vt < vt_end) {
        const int row = min(vt * 16 + r16, VOCAB - 1);
        const __bf16* p = Eb + (size_t)row * DIM + hi * 8;
        b0 = *(const bf16x8*)p;
        b1 = *(const bf16x8*)(p + 32);
    }
    while (vt < vt_end) {
        const bf16x8 c0 = b0, c1 = b1;
        const int vt_cur = vt;
        vt += 4;
        if (vt < vt_end) {
            const int row = min(vt * 16 + r16, VOCAB - 1);
            const __bf16* p = Eb + (size_t)row * DIM + hi * 8;
            b0 = *(const bf16x8*)p;
            b1 = *(const bf16x8*)(p + 32);
        }
        if (vt_cur < VT_FULL) {
            #pragma unroll
            for (int t = 0; t < 4; ++t) {
                f32x4 acc = {0.f, 0.f, 0.f, 0.f};
                acc = __builtin_amdgcn_mfma_f32_16x16x32_bf16(a[t][0], c0, acc, 0, 0, 0);
                acc = __builtin_amdgcn_mfma_f32_16x16x32_bf16(a[t][1], c1, acc, 0, 0, 0);
                #pragma unroll
                for (int r = 0; r < 4; ++r) ssum[t][r] += __expf(acc[r]);
            }
        } else {
            const bool valid = (vt_cur * 16 + r16) < VOCAB;
            #pragma unroll
            for (int t = 0; t < 4; ++t) {
                f32x4 acc = {0.f, 0.f, 0.f, 0.f};
                acc = __builtin_amdgcn_mfma_f32_16x16x32_bf16(a[t][0], c0, acc, 0, 0, 0);
                acc = __builtin_amdgcn_mfma_f32_16x16x32_bf16(a[t][1], c1, acc, 0, 0, 0);
                #pragma unroll
                for (int r = 0; r < 4; ++r) ssum[t][r] += valid ? __expf(acc[r]) : 0.f;
            }
        }
    }

    #pragma unroll
    for (int t = 0; t < 4; ++t)
        #pragma unroll
        for (int r = 0; r < 4; ++r) {
            float v = ssum[t][r];
            v += __shfl_xor(v, 1);
            v += __shfl_xor(v, 2);
            v += __shfl_xor(v, 4);
            v += __shfl_xor(v, 8);
            ssum[t][r] = v;
        }

    if (r16 == 0) {
        const int wslot = chunk * 4 + wave;
        #pragma unroll
        for (int t = 0; t < 4; ++t)
            #pragma unroll
            for (int r = 0; r < 4; ++r) {
                const int row = bg * 64 + t * 16 + hi * 4 + r;
                partials[(size_t)wslot * B_TOT + row] = ssum[t][r];
            }
    }
}

// ---------------------------------------------------------------------------
// Kernel C: reduce partials, exact fp32 pred logit, emit prob.
// ---------------------------------------------------------------------------
__global__ __launch_bounds__(256) void finalize_kernel(
    const float* __restrict__ Q,
    const float* __restrict__ item_emb,
    const int*   __restrict__ pred,
    const float* __restrict__ partials,
    float*       __restrict__ out)
{
    const int b = blockIdx.x * 256 + threadIdx.x;

    float S = 0.f;
    for (int w = 0; w < NC * 4; ++w)
        S += partials[(size_t)w * B_TOT + b];

    const int pv = pred[b];
    float acc = 0.f;
    const float4* e4 = (const float4*)(item_emb + (long)pv * DIM);
    const float4* q4 = (const float4*)(Q + b * DIM);
    #pragma unroll
    for (int i = 0; i < DIM / 4; ++i) {
        const float4 e = e4[i];
        const float4 q = q4[i];
        acc += e.x*q.x + e.y*q.y + e.z*q.z + e.w*q.w;
    }
    out[b] = __expf(acc) / S;
}

// ---------------------------------------------------------------------------
extern "C" void kernel_launch(void* const* d_in, const int* in_sizes, int n_in,
                              void* d_out, int out_size, void* d_ws, size_t ws_size,
                              hipStream_t stream)
{
    const int*   log_seqs = (const int*)  d_in[0];
    const int*   pred     = (const int*)  d_in[1];
    const float* item_emb = (const float*)d_in[2];
    const float* attn_key = (const float*)d_in[3];
    const float* pos_emb  = (const float*)d_in[4];
    float*       out      = (float*)d_out;

    char* ws = (char*)d_ws;
    __bf16* Eb       = (__bf16*)ws;                                   // 12,800,128 B
    __bf16* Qb       = (__bf16*)(ws + (size_t)VOCAB * DIM * 2);       // 131,072 B
    float*  Qf       = (float*) (ws + (size_t)VOCAB * DIM * 2 + (size_t)B_TOT * DIM * 2);
    float*  partials = (float*) ((char*)Qf + (size_t)B_TOT * DIM * 4); // [256][1024] f32

    {   // convert item_emb -> bf16
        const long n8 = ((long)VOCAB * DIM) / 8;                      // 800,008
        const int blocks = (int)((n8 + 255) / 256);
        convert_kernel<<<blocks, 256, 0, stream>>>(item_emb, Eb);
    }
    pool_kernel<<<B_TOT, 256, 0, stream>>>(log_seqs, item_emb, attn_key, pos_emb, Qf, Qb);
    logits_mfma<<<NBG * NC, 256, 0, stream>>>(Eb, Qb, partials);
    finalize_kernel<<<B_TOT / 256, 256, 0, stream>>>(Qf, item_emb, pred, partials, out);
}

// Round 4
// 75.207 us; speedup vs baseline: 7.2172x; 1.2063x over previous
//
#include <hip/hip_runtime.h>
#include <math.h>

#define B_TOT   1024
#define L_SEQ   200
#define DIM     64
#define VOCAB   100001
#define NEG_BIG (-1e15f)
#define SEQ_STRIDE 68                   // 64 + 4 pad: b128 writes conflict-free

typedef __bf16 bf16x8 __attribute__((ext_vector_type(8)));
typedef float  f32x4  __attribute__((ext_vector_type(4)));

// ---------------------------------------------------------------------------
// Kernel 0: convert item_emb fp32 -> bf16 (row-major [VOCAB][64])
// ---------------------------------------------------------------------------
__global__ __launch_bounds__(256) void convert_kernel(
    const float* __restrict__ src,
    __bf16*      __restrict__ dst)
{
    const long n = (long)VOCAB * DIM;            // 6,400,064 = 8 * 800,008
    const long i = ((long)blockIdx.x * 256 + threadIdx.x) * 8;
    if (i + 8 > n) return;
    const float4 f0 = ((const float4*)(src + i))[0];
    const float4 f1 = ((const float4*)(src + i))[1];
    bf16x8 o;
    o[0] = (__bf16)f0.x; o[1] = (__bf16)f0.y; o[2] = (__bf16)f0.z; o[3] = (__bf16)f0.w;
    o[4] = (__bf16)f1.x; o[5] = (__bf16)f1.y; o[6] = (__bf16)f1.z; o[7] = (__bf16)f1.w;
    *(bf16x8*)(dst + i) = o;
}

// ---------------------------------------------------------------------------
// Kernel A: attention pooling. 256 threads (4 waves) per batch row.
// Phase 1: thread l gathers its E row ONCE, computes seq[l][:] = 8*E+pos,
//          stores it to LDS (padded stride), and computes sim[l].
// Phase 2: block softmax.
// Phase 3: Q[d] = inv * sum_l p[l]*s_seq[l][d] — pure LDS column sum,
//          L split across the 4 waves, no global re-gather.
// ---------------------------------------------------------------------------
__global__ __launch_bounds__(256) void pool_kernel(
    const int*   __restrict__ log_seqs,
    const float* __restrict__ item_emb,
    const float* __restrict__ attn_key,
    const float* __restrict__ pos_emb,
    float*       __restrict__ Q,
    __bf16*      __restrict__ Qb)
{
    const int b    = blockIdx.x;
    const int t    = threadIdx.x;
    const int wave = t >> 6;
    const int lane = t & 63;

    __shared__ float s_seq[L_SEQ][SEQ_STRIDE];   // 54,400 B
    __shared__ float s_attn[L_SEQ];
    __shared__ float s_red[4];
    __shared__ float s_q[4][DIM];

    // ---- phase 1: seq row -> LDS, sim[l] ----------------------------------
    float sim = -INFINITY;
    if (t < L_SEQ) {
        const int id = log_seqs[(long)b * L_SEQ + t];
        if (id == 0) {
            sim = NEG_BIG;
            #pragma unroll
            for (int i = 0; i < DIM / 4; ++i)
                *(float4*)(&s_seq[t][4 * i]) = make_float4(0.f, 0.f, 0.f, 0.f);
        } else {
            float acc = 0.f;
            const float4* e4 = (const float4*)(item_emb + (long)id * DIM);
            const float4* p4 = (const float4*)(pos_emb + t * DIM);
            #pragma unroll
            for (int i = 0; i < DIM / 4; ++i) {
                const float4 e = e4[i];
                const float4 p = p4[i];
                float4 f;
                f.x = fmaf(8.f, e.x, p.x);
                f.y = fmaf(8.f, e.y, p.y);
                f.z = fmaf(8.f, e.z, p.z);
                f.w = fmaf(8.f, e.w, p.w);
                *(float4*)(&s_seq[t][4 * i]) = f;
                // attn_key reads are thread-uniform -> scalar loads
                acc += f.x * attn_key[4*i+0] + f.y * attn_key[4*i+1]
                     + f.z * attn_key[4*i+2] + f.w * attn_key[4*i+3];
            }
            sim = acc;
        }
    }

    // ---- phase 2: block softmax over l -------------------------------------
    float m = sim;
    #pragma unroll
    for (int off = 32; off > 0; off >>= 1) m = fmaxf(m, __shfl_xor(m, off));
    if (lane == 0) s_red[wave] = m;
    __syncthreads();
    m = fmaxf(fmaxf(s_red[0], s_red[1]), fmaxf(s_red[2], s_red[3]));
    __syncthreads();                             // all waves read s_red

    float p = (t < L_SEQ) ? __expf(sim - m) : 0.f;
    if (t < L_SEQ) s_attn[t] = p;
    float ls = p;
    #pragma unroll
    for (int off = 32; off > 0; off >>= 1) ls += __shfl_xor(ls, off);
    if (lane == 0) s_red[wave] = ls;
    __syncthreads();
    const float inv = 1.0f / (s_red[0] + s_red[1] + s_red[2] + s_red[3]);

    // ---- phase 3: Q accumulation from LDS, L split across waves ------------
    float q = 0.f;
    const int l0 = wave * (L_SEQ / 4);
    #pragma unroll 2
    for (int l = l0; l < l0 + (L_SEQ / 4); ++l)
        q = fmaf(s_attn[l], s_seq[l][lane], q);
    s_q[wave][lane] = q;
    __syncthreads();

    if (t < DIM) {
        const float qq = (s_q[0][t] + s_q[1][t] + s_q[2][t] + s_q[3][t]) * inv;
        Q[b * DIM + t]  = qq;
        Qb[b * DIM + t] = (__bf16)qq;
    }
}

// ---------------------------------------------------------------------------
// Kernel B: bf16 MFMA logits GEMM + exp-sum partials (no max needed: logits
// are bounded, exp-safe; identical to max-subtracted softmax).
// XCD-aware block decode: XCD k owns chunks == k (mod 8) -> per-XCD working
// set = 8 chunks x 200 KB E + 128 KB Qb, L2-resident; each E chunk crosses
// L3 once per XCD instead of 16x.
// ---------------------------------------------------------------------------
#define NC        64                    // vocab chunks
#define NBG       16                    // batch groups (1024/64)
#define VT_TOTAL  6251                  // ceil(100001/16)
#define VT_FULL   6250

__global__ __launch_bounds__(256) void logits_mfma(
    const __bf16* __restrict__ Eb,      // [VOCAB][64]
    const __bf16* __restrict__ Qb,      // [1024][64]
    float*        __restrict__ partials) // [NC*4][1024]
{
    const int bid   = blockIdx.x;
    const int xcd   = bid & 7;          // HW round-robins blockIdx across XCDs
    const int idx   = bid >> 3;         // 0..127 within this XCD
    const int chunk = xcd + 8 * (idx >> 4);   // chunks == xcd (mod 8)
    const int bg    = idx & 15;
    const int wave  = threadIdx.x >> 6;
    const int lane  = threadIdx.x & 63;
    const int r16   = lane & 15;
    const int hi    = lane >> 4;

    bf16x8 a[4][2];
    #pragma unroll
    for (int t = 0; t < 4; ++t)
        #pragma unroll
        for (int s = 0; s < 2; ++s)
            a[t][s] = *(const bf16x8*)(Qb + ((bg*64 + t*16 + r16) * DIM) + s*32 + hi*8);

    const int per    = (VT_TOTAL + NC - 1) / NC;   // 98
    const int vt_end = min((chunk + 1) * per, VT_TOTAL);
    int vt = chunk * per + wave;

    float ssum[4][4];
    #pragma unroll
    for (int t = 0; t < 4; ++t)
        #pragma unroll
        for (int r = 0; r < 4; ++r) ssum[t][r] = 0.f;

    bf16x8 b0, b1;
    if (vt < vt_end) {
        const int row = min(vt * 16 + r16, VOCAB - 1);
        const __bf16* p = Eb + (size_t)row * DIM + hi * 8;
        b0 = *(const bf16x8*)p;
        b1 = *(const bf16x8*)(p + 32);
    }
    while (vt < vt_end) {
        const bf16x8 c0 = b0, c1 = b1;
        const int vt_cur = vt;
        vt += 4;
        if (vt < vt_end) {
            const int row = min(vt * 16 + r16, VOCAB - 1);
            const __bf16* p = Eb + (size_t)row * DIM + hi * 8;
            b0 = *(const bf16x8*)p;
            b1 = *(const bf16x8*)(p + 32);
        }
        if (vt_cur < VT_FULL) {
            #pragma unroll
            for (int t = 0; t < 4; ++t) {
                f32x4 acc = {0.f, 0.f, 0.f, 0.f};
                acc = __builtin_amdgcn_mfma_f32_16x16x32_bf16(a[t][0], c0, acc, 0, 0, 0);
                acc = __builtin_amdgcn_mfma_f32_16x16x32_bf16(a[t][1], c1, acc, 0, 0, 0);
                #pragma unroll
                for (int r = 0; r < 4; ++r) ssum[t][r] += __expf(acc[r]);
            }
        } else {
            const bool valid = (vt_cur * 16 + r16) < VOCAB;
            #pragma unroll
            for (int t = 0; t < 4; ++t) {
                f32x4 acc = {0.f, 0.f, 0.f, 0.f};
                acc = __builtin_amdgcn_mfma_f32_16x16x32_bf16(a[t][0], c0, acc, 0, 0, 0);
                acc = __builtin_amdgcn_mfma_f32_16x16x32_bf16(a[t][1], c1, acc, 0, 0, 0);
                #pragma unroll
                for (int r = 0; r < 4; ++r) ssum[t][r] += valid ? __expf(acc[r]) : 0.f;
            }
        }
    }

    #pragma unroll
    for (int t = 0; t < 4; ++t)
        #pragma unroll
        for (int r = 0; r < 4; ++r) {
            float v = ssum[t][r];
            v += __shfl_xor(v, 1);
            v += __shfl_xor(v, 2);
            v += __shfl_xor(v, 4);
            v += __shfl_xor(v, 8);
            ssum[t][r] = v;
        }

    if (r16 == 0) {
        const int wslot = chunk * 4 + wave;
        #pragma unroll
        for (int t = 0; t < 4; ++t)
            #pragma unroll
            for (int r = 0; r < 4; ++r) {
                const int row = bg * 64 + t * 16 + hi * 4 + r;
                partials[(size_t)wslot * B_TOT + row] = ssum[t][r];
            }
    }
}

// ---------------------------------------------------------------------------
// Kernel C: reduce partials, exact fp32 pred logit, emit prob.
// ---------------------------------------------------------------------------
__global__ __launch_bounds__(256) void finalize_kernel(
    const float* __restrict__ Q,
    const float* __restrict__ item_emb,
    const int*   __restrict__ pred,
    const float* __restrict__ partials,
    float*       __restrict__ out)
{
    const int b = blockIdx.x * 256 + threadIdx.x;

    float S = 0.f;
    for (int w = 0; w < NC * 4; ++w)
        S += partials[(size_t)w * B_TOT + b];

    const int pv = pred[b];
    float acc = 0.f;
    const float4* e4 = (const float4*)(item_emb + (long)pv * DIM);
    const float4* q4 = (const float4*)(Q + b * DIM);
    #pragma unroll
    for (int i = 0; i < DIM / 4; ++i) {
        const float4 e = e4[i];
        const float4 q = q4[i];
        acc += e.x*q.x + e.y*q.y + e.z*q.z + e.w*q.w;
    }
    out[b] = __expf(acc) / S;
}

// ---------------------------------------------------------------------------
extern "C" void kernel_launch(void* const* d_in, const int* in_sizes, int n_in,
                              void* d_out, int out_size, void* d_ws, size_t ws_size,
                              hipStream_t stream)
{
    const int*   log_seqs = (const int*)  d_in[0];
    const int*   pred     = (const int*)  d_in[1];
    const float* item_emb = (const float*)d_in[2];
    const float* attn_key = (const float*)d_in[3];
    const float* pos_emb  = (const float*)d_in[4];
    float*       out      = (float*)d_out;

    char* ws = (char*)d_ws;
    __bf16* Eb       = (__bf16*)ws;                                   // 12,800,128 B
    __bf16* Qb       = (__bf16*)(ws + (size_t)VOCAB * DIM * 2);       // 131,072 B
    float*  Qf       = (float*) (ws + (size_t)VOCAB * DIM * 2 + (size_t)B_TOT * DIM * 2);
    float*  partials = (float*) ((char*)Qf + (size_t)B_TOT * DIM * 4); // [256][1024] f32

    {   // convert item_emb -> bf16
        const long n8 = ((long)VOCAB * DIM) / 8;                      // 800,008
        const int blocks = (int)((n8 + 255) / 256);
        convert_kernel<<<blocks, 256, 0, stream>>>(item_emb, Eb);
    }
    pool_kernel<<<B_TOT, 256, 0, stream>>>(log_seqs, item_emb, attn_key, pos_emb, Qf, Qb);
    logits_mfma<<<NBG * NC, 256, 0, stream>>>(Eb, Qb, partials);
    finalize_kernel<<<B_TOT / 256, 256, 0, stream>>>(Qf, item_emb, pred, partials, out);
}

// Round 5
// 69.877 us; speedup vs baseline: 7.7677x; 1.0763x over previous
//
#include <hip/hip_runtime.h>
#include <math.h>

#define B_TOT   1024
#define L_SEQ   200
#define DIM     64
#define VOCAB   100001
#define NEG_BIG (-1e15f)
#define SEQ_STRIDE 68                   // 64 + 4 pad: b128 writes conflict-free

typedef __bf16 bf16x8 __attribute__((ext_vector_type(8)));
typedef float  f32x4  __attribute__((ext_vector_type(4)));

// ---------------------------------------------------------------------------
// Kernel A: fused convert(E->bf16) + attention pooling.
// Prologue: grid-stride bf16 conversion of item_emb (streaming, overlaps the
//           gather latency of the pool phases).
// Phase 1: thread l gathers its E row ONCE, computes seq[l][:] = 8*E+pos,
//          stores it to LDS (padded stride), and computes sim[l].
// Phase 2: block softmax.   Phase 3: LDS column sum, L split across waves.
// ---------------------------------------------------------------------------
__global__ __launch_bounds__(256) void pool_kernel(
    const int*   __restrict__ log_seqs,
    const float* __restrict__ item_emb,
    const float* __restrict__ attn_key,
    const float* __restrict__ pos_emb,
    float*       __restrict__ Q,
    __bf16*      __restrict__ Qb,
    __bf16*      __restrict__ Eb)
{
    const int b    = blockIdx.x;
    const int t    = threadIdx.x;
    const int wave = t >> 6;
    const int lane = t & 63;

    __shared__ float s_seq[L_SEQ][SEQ_STRIDE];   // 54,400 B
    __shared__ float s_attn[L_SEQ];
    __shared__ float s_red[4];
    __shared__ float s_q[4][DIM];

    // ---- prologue: convert slice of item_emb -> bf16 -----------------------
    {
        const long n8 = ((long)VOCAB * DIM) / 8;             // 800,008 groups
        for (long g = (long)b * 256 + t; g < n8; g += (long)gridDim.x * 256) {
            const long i = g * 8;
            const float4 f0 = ((const float4*)(item_emb + i))[0];
            const float4 f1 = ((const float4*)(item_emb + i))[1];
            bf16x8 o;
            o[0] = (__bf16)f0.x; o[1] = (__bf16)f0.y; o[2] = (__bf16)f0.z; o[3] = (__bf16)f0.w;
            o[4] = (__bf16)f1.x; o[5] = (__bf16)f1.y; o[6] = (__bf16)f1.z; o[7] = (__bf16)f1.w;
            *(bf16x8*)(Eb + i) = o;
        }
    }

    // ---- phase 1: seq row -> LDS, sim[l] ----------------------------------
    float sim = -INFINITY;
    if (t < L_SEQ) {
        const int id = log_seqs[(long)b * L_SEQ + t];
        if (id == 0) {
            sim = NEG_BIG;
            #pragma unroll
            for (int i = 0; i < DIM / 4; ++i)
                *(float4*)(&s_seq[t][4 * i]) = make_float4(0.f, 0.f, 0.f, 0.f);
        } else {
            float acc = 0.f;
            const float4* e4 = (const float4*)(item_emb + (long)id * DIM);
            const float4* p4 = (const float4*)(pos_emb + t * DIM);
            #pragma unroll
            for (int i = 0; i < DIM / 4; ++i) {
                const float4 e = e4[i];
                const float4 p = p4[i];
                float4 f;
                f.x = fmaf(8.f, e.x, p.x);
                f.y = fmaf(8.f, e.y, p.y);
                f.z = fmaf(8.f, e.z, p.z);
                f.w = fmaf(8.f, e.w, p.w);
                *(float4*)(&s_seq[t][4 * i]) = f;
                // attn_key reads are thread-uniform -> scalar loads
                acc += f.x * attn_key[4*i+0] + f.y * attn_key[4*i+1]
                     + f.z * attn_key[4*i+2] + f.w * attn_key[4*i+3];
            }
            sim = acc;
        }
    }

    // ---- phase 2: block softmax over l -------------------------------------
    float m = sim;
    #pragma unroll
    for (int off = 32; off > 0; off >>= 1) m = fmaxf(m, __shfl_xor(m, off));
    if (lane == 0) s_red[wave] = m;
    __syncthreads();
    m = fmaxf(fmaxf(s_red[0], s_red[1]), fmaxf(s_red[2], s_red[3]));
    __syncthreads();                             // all waves read s_red

    float p = (t < L_SEQ) ? __expf(sim - m) : 0.f;
    if (t < L_SEQ) s_attn[t] = p;
    float ls = p;
    #pragma unroll
    for (int off = 32; off > 0; off >>= 1) ls += __shfl_xor(ls, off);
    if (lane == 0) s_red[wave] = ls;
    __syncthreads();
    const float inv = 1.0f / (s_red[0] + s_red[1] + s_red[2] + s_red[3]);

    // ---- phase 3: Q accumulation from LDS, L split across waves ------------
    float q = 0.f;
    const int l0 = wave * (L_SEQ / 4);
    #pragma unroll 2
    for (int l = l0; l < l0 + (L_SEQ / 4); ++l)
        q = fmaf(s_attn[l], s_seq[l][lane], q);
    s_q[wave][lane] = q;
    __syncthreads();

    if (t < DIM) {
        const float qq = (s_q[0][t] + s_q[1][t] + s_q[2][t] + s_q[3][t]) * inv;
        Q[b * DIM + t]  = qq;
        Qb[b * DIM + t] = (__bf16)qq;
    }
}

// ---------------------------------------------------------------------------
// Kernel B: bf16 MFMA logits GEMM + exp-sum partials (no max needed: logits
// are bounded, exp-safe; identical to max-subtracted softmax).
// 128 batch rows per block (8 b-tiles) -> E read 8x total instead of 16x.
// XCD-aware decode: XCD k owns chunks == k (mod 8); bg cycles fastest among
// consecutive blocks so each 200 KB chunk is L2-resident across its 8 bgs.
// ---------------------------------------------------------------------------
#define NC        64                    // vocab chunks
#define NBG       8                     // batch groups (1024/128)
#define VT_TOTAL  6251                  // ceil(100001/16)
#define VT_FULL   6250

__global__ __launch_bounds__(256) void logits_mfma(
    const __bf16* __restrict__ Eb,      // [VOCAB][64]
    const __bf16* __restrict__ Qb,      // [1024][64]
    float*        __restrict__ partials) // [NC*4][1024]
{
    const int bid   = blockIdx.x;                 // 0..511
    const int xcd   = bid & 7;          // HW round-robins blockIdx across XCDs
    const int idx   = bid >> 3;         // 0..63 within this XCD
    const int chunk = xcd + 8 * (idx >> 3);       // chunks == xcd (mod 8)
    const int bg    = idx & 7;
    const int wave  = threadIdx.x >> 6;
    const int lane  = threadIdx.x & 63;
    const int r16   = lane & 15;
    const int hi    = lane >> 4;

    bf16x8 a[8][2];
    #pragma unroll
    for (int t = 0; t < 8; ++t)
        #pragma unroll
        for (int s = 0; s < 2; ++s)
            a[t][s] = *(const bf16x8*)(Qb + ((bg*128 + t*16 + r16) * DIM) + s*32 + hi*8);

    const int per    = (VT_TOTAL + NC - 1) / NC;   // 98
    const int vt_end = min((chunk + 1) * per, VT_TOTAL);
    int vt = chunk * per + wave;

    float ssum[8][4];
    #pragma unroll
    for (int t = 0; t < 8; ++t)
        #pragma unroll
        for (int r = 0; r < 4; ++r) ssum[t][r] = 0.f;

    bf16x8 b0, b1;
    if (vt < vt_end) {
        const int row = min(vt * 16 + r16, VOCAB - 1);
        const __bf16* p = Eb + (size_t)row * DIM + hi * 8;
        b0 = *(const bf16x8*)p;
        b1 = *(const bf16x8*)(p + 32);
    }
    while (vt < vt_end) {
        const bf16x8 c0 = b0, c1 = b1;
        const int vt_cur = vt;
        vt += 4;
        if (vt < vt_end) {
            const int row = min(vt * 16 + r16, VOCAB - 1);
            const __bf16* p = Eb + (size_t)row * DIM + hi * 8;
            b0 = *(const bf16x8*)p;
            b1 = *(const bf16x8*)(p + 32);
        }
        if (vt_cur < VT_FULL) {
            #pragma unroll
            for (int t = 0; t < 8; ++t) {
                f32x4 acc = {0.f, 0.f, 0.f, 0.f};
                acc = __builtin_amdgcn_mfma_f32_16x16x32_bf16(a[t][0], c0, acc, 0, 0, 0);
                acc = __builtin_amdgcn_mfma_f32_16x16x32_bf16(a[t][1], c1, acc, 0, 0, 0);
                #pragma unroll
                for (int r = 0; r < 4; ++r) ssum[t][r] += __expf(acc[r]);
            }
        } else {
            const bool valid = (vt_cur * 16 + r16) < VOCAB;
            #pragma unroll
            for (int t = 0; t < 8; ++t) {
                f32x4 acc = {0.f, 0.f, 0.f, 0.f};
                acc = __builtin_amdgcn_mfma_f32_16x16x32_bf16(a[t][0], c0, acc, 0, 0, 0);
                acc = __builtin_amdgcn_mfma_f32_16x16x32_bf16(a[t][1], c1, acc, 0, 0, 0);
                #pragma unroll
                for (int r = 0; r < 4; ++r) ssum[t][r] += valid ? __expf(acc[r]) : 0.f;
            }
        }
    }

    #pragma unroll
    for (int t = 0; t < 8; ++t)
        #pragma unroll
        for (int r = 0; r < 4; ++r) {
            float v = ssum[t][r];
            v += __shfl_xor(v, 1);
            v += __shfl_xor(v, 2);
            v += __shfl_xor(v, 4);
            v += __shfl_xor(v, 8);
            ssum[t][r] = v;
        }

    if (r16 == 0) {
        const int wslot = chunk * 4 + wave;
        #pragma unroll
        for (int t = 0; t < 8; ++t)
            #pragma unroll
            for (int r = 0; r < 4; ++r) {
                const int row = bg * 128 + t * 16 + hi * 4 + r;
                partials[(size_t)wslot * B_TOT + row] = ssum[t][r];
            }
    }
}

// ---------------------------------------------------------------------------
// Kernel C: reduce partials, exact fp32 pred logit, emit prob.
// ---------------------------------------------------------------------------
__global__ __launch_bounds__(256) void finalize_kernel(
    const float* __restrict__ Q,
    const float* __restrict__ item_emb,
    const int*   __restrict__ pred,
    const float* __restrict__ partials,
    float*       __restrict__ out)
{
    const int b = blockIdx.x * 256 + threadIdx.x;

    float S = 0.f;
    for (int w = 0; w < NC * 4; ++w)
        S += partials[(size_t)w * B_TOT + b];

    const int pv = pred[b];
    float acc = 0.f;
    const float4* e4 = (const float4*)(item_emb + (long)pv * DIM);
    const float4* q4 = (const float4*)(Q + b * DIM);
    #pragma unroll
    for (int i = 0; i < DIM / 4; ++i) {
        const float4 e = e4[i];
        const float4 q = q4[i];
        acc += e.x*q.x + e.y*q.y + e.z*q.z + e.w*q.w;
    }
    out[b] = __expf(acc) / S;
}

// ---------------------------------------------------------------------------
extern "C" void kernel_launch(void* const* d_in, const int* in_sizes, int n_in,
                              void* d_out, int out_size, void* d_ws, size_t ws_size,
                              hipStream_t stream)
{
    const int*   log_seqs = (const int*)  d_in[0];
    const int*   pred     = (const int*)  d_in[1];
    const float* item_emb = (const float*)d_in[2];
    const float* attn_key = (const float*)d_in[3];
    const float* pos_emb  = (const float*)d_in[4];
    float*       out      = (float*)d_out;

    char* ws = (char*)d_ws;
    __bf16* Eb       = (__bf16*)ws;                                   // 12,800,128 B
    __bf16* Qb       = (__bf16*)(ws + (size_t)VOCAB * DIM * 2);       // 131,072 B
    float*  Qf       = (float*) (ws + (size_t)VOCAB * DIM * 2 + (size_t)B_TOT * DIM * 2);
    float*  partials = (float*) ((char*)Qf + (size_t)B_TOT * DIM * 4); // [256][1024] f32

    pool_kernel<<<B_TOT, 256, 0, stream>>>(log_seqs, item_emb, attn_key, pos_emb, Qf, Qb, Eb);
    logits_mfma<<<NBG * NC, 256, 0, stream>>>(Eb, Qb, partials);
    finalize_kernel<<<B_TOT / 256, 256, 0, stream>>>(Qf, item_emb, pred, partials, out);
}

// Round 6
// 68.602 us; speedup vs baseline: 7.9121x; 1.0186x over previous
//
#include <hip/hip_runtime.h>
#include <math.h>

#define B_TOT   1024
#define L_SEQ   200
#define DIM     64
#define VOCAB   100001
#define NEG_BIG (-1e15f)
#define SEQ_STRIDE 68                   // 64 + 4 pad: b128 writes conflict-free

typedef __bf16 bf16x8 __attribute__((ext_vector_type(8)));
typedef float  f32x4  __attribute__((ext_vector_type(4)));

// ---------------------------------------------------------------------------
// Kernel A: fused convert(E->bf16) + attention pooling.
// Prologue: grid-stride bf16 conversion of item_emb (streaming, overlaps the
//           gather latency of the pool phases).
// Phase 1: thread l gathers its E row ONCE, computes seq[l][:] = 8*E+pos,
//          stores it to LDS (padded stride), and computes sim[l].
// Phase 2: block softmax.   Phase 3: LDS column sum, L split across waves.
// ---------------------------------------------------------------------------
__global__ __launch_bounds__(256) void pool_kernel(
    const int*   __restrict__ log_seqs,
    const float* __restrict__ item_emb,
    const float* __restrict__ attn_key,
    const float* __restrict__ pos_emb,
    float*       __restrict__ Q,
    __bf16*      __restrict__ Qb,
    __bf16*      __restrict__ Eb)
{
    const int b    = blockIdx.x;
    const int t    = threadIdx.x;
    const int wave = t >> 6;
    const int lane = t & 63;

    __shared__ float s_seq[L_SEQ][SEQ_STRIDE];   // 54,400 B
    __shared__ float s_attn[L_SEQ];
    __shared__ float s_red[4];
    __shared__ float s_q[4][DIM];

    // ---- prologue: convert slice of item_emb -> bf16 -----------------------
    {
        const long n8 = ((long)VOCAB * DIM) / 8;             // 800,008 groups
        for (long g = (long)b * 256 + t; g < n8; g += (long)gridDim.x * 256) {
            const long i = g * 8;
            const float4 f0 = ((const float4*)(item_emb + i))[0];
            const float4 f1 = ((const float4*)(item_emb + i))[1];
            bf16x8 o;
            o[0] = (__bf16)f0.x; o[1] = (__bf16)f0.y; o[2] = (__bf16)f0.z; o[3] = (__bf16)f0.w;
            o[4] = (__bf16)f1.x; o[5] = (__bf16)f1.y; o[6] = (__bf16)f1.z; o[7] = (__bf16)f1.w;
            *(bf16x8*)(Eb + i) = o;
        }
    }

    // ---- phase 1: seq row -> LDS, sim[l] ----------------------------------
    float sim = -INFINITY;
    if (t < L_SEQ) {
        const int id = log_seqs[(long)b * L_SEQ + t];
        if (id == 0) {
            sim = NEG_BIG;
            #pragma unroll
            for (int i = 0; i < DIM / 4; ++i)
                *(float4*)(&s_seq[t][4 * i]) = make_float4(0.f, 0.f, 0.f, 0.f);
        } else {
            float acc = 0.f;
            const float4* e4 = (const float4*)(item_emb + (long)id * DIM);
            const float4* p4 = (const float4*)(pos_emb + t * DIM);
            #pragma unroll
            for (int i = 0; i < DIM / 4; ++i) {
                const float4 e = e4[i];
                const float4 p = p4[i];
                float4 f;
                f.x = fmaf(8.f, e.x, p.x);
                f.y = fmaf(8.f, e.y, p.y);
                f.z = fmaf(8.f, e.z, p.z);
                f.w = fmaf(8.f, e.w, p.w);
                *(float4*)(&s_seq[t][4 * i]) = f;
                // attn_key reads are thread-uniform -> scalar loads
                acc += f.x * attn_key[4*i+0] + f.y * attn_key[4*i+1]
                     + f.z * attn_key[4*i+2] + f.w * attn_key[4*i+3];
            }
            sim = acc;
        }
    }

    // ---- phase 2: block softmax over l -------------------------------------
    float m = sim;
    #pragma unroll
    for (int off = 32; off > 0; off >>= 1) m = fmaxf(m, __shfl_xor(m, off));
    if (lane == 0) s_red[wave] = m;
    __syncthreads();
    m = fmaxf(fmaxf(s_red[0], s_red[1]), fmaxf(s_red[2], s_red[3]));
    __syncthreads();                             // all waves read s_red

    float p = (t < L_SEQ) ? __expf(sim - m) : 0.f;
    if (t < L_SEQ) s_attn[t] = p;
    float ls = p;
    #pragma unroll
    for (int off = 32; off > 0; off >>= 1) ls += __shfl_xor(ls, off);
    if (lane == 0) s_red[wave] = ls;
    __syncthreads();
    const float inv = 1.0f / (s_red[0] + s_red[1] + s_red[2] + s_red[3]);

    // ---- phase 3: Q accumulation from LDS, L split across waves ------------
    float q = 0.f;
    const int l0 = wave * (L_SEQ / 4);
    #pragma unroll 2
    for (int l = l0; l < l0 + (L_SEQ / 4); ++l)
        q = fmaf(s_attn[l], s_seq[l][lane], q);
    s_q[wave][lane] = q;
    __syncthreads();

    if (t < DIM) {
        const float qq = (s_q[0][t] + s_q[1][t] + s_q[2][t] + s_q[3][t]) * inv;
        Q[b * DIM + t]  = qq;
        Qb[b * DIM + t] = (__bf16)qq;
    }
}

// ---------------------------------------------------------------------------
// Kernel B: bf16 MFMA logits GEMM + exp-sum partials (no max needed: logits
// are bounded, exp-safe; identical to max-subtracted softmax).
// 128 batch rows per block (8 b-tiles), NC=128 chunks -> 1024 blocks for
// occupancy; depth-2 register prefetch (4 clamped loads in flight per wave);
// cross-wave LDS reduce -> one partial slot per (chunk,row).
// XCD-aware decode: XCD k owns chunks == k (mod 8); bg cycles fastest.
// ---------------------------------------------------------------------------
#define NC        128                   // vocab chunks
#define NBG       8                     // batch groups (1024/128)
#define VT_TOTAL  6251                  // ceil(100001/16)
#define VT_FULL   6250

__global__ __launch_bounds__(256) void logits_mfma(
    const __bf16* __restrict__ Eb,      // [VOCAB][64]
    const __bf16* __restrict__ Qb,      // [1024][64]
    float*        __restrict__ partials) // [NC][1024]
{
    const int bid   = blockIdx.x;                 // 0..1023
    const int xcd   = bid & 7;          // HW round-robins blockIdx across XCDs
    const int idx   = bid >> 3;         // 0..127 within this XCD
    const int chunk = xcd + 8 * (idx >> 3);       // chunks == xcd (mod 8)
    const int bg    = idx & 7;
    const int wave  = threadIdx.x >> 6;
    const int lane  = threadIdx.x & 63;
    const int r16   = lane & 15;
    const int hi    = lane >> 4;

    __shared__ float s_part[4][128];

    bf16x8 a[8][2];
    #pragma unroll
    for (int t = 0; t < 8; ++t)
        #pragma unroll
        for (int s = 0; s < 2; ++s)
            a[t][s] = *(const bf16x8*)(Qb + ((bg*128 + t*16 + r16) * DIM) + s*32 + hi*8);

    const int per    = (VT_TOTAL + NC - 1) / NC;   // 49
    const int vt_end = min((chunk + 1) * per, VT_TOTAL);
    int vt = chunk * per + wave;

    float ssum[8][4];
    #pragma unroll
    for (int t = 0; t < 8; ++t)
        #pragma unroll
        for (int r = 0; r < 4; ++r) ssum[t][r] = 0.f;

    // clamped loads are always in-bounds; prefetch past vt_end is harmless
    #define LOADB(dst0, dst1, vti) do {                                       \
        const int _row = min((vti) * 16 + r16, VOCAB - 1);                    \
        const __bf16* _p = Eb + (size_t)_row * DIM + hi * 8;                  \
        dst0 = *(const bf16x8*)_p;                                            \
        dst1 = *(const bf16x8*)(_p + 32);                                     \
    } while (0)

    bf16x8 b0, b1, d0, d1;
    LOADB(b0, b1, vt);
    LOADB(d0, d1, vt + 4);

    while (vt < vt_end) {
        const bf16x8 c00 = b0, c01 = b1, c10 = d0, c11 = d1;
        const int v0 = vt, v1 = vt + 4;
        vt += 8;
        LOADB(b0, b1, vt);
        LOADB(d0, d1, vt + 4);

        // ---- compute v0 ----
        if (v0 < VT_FULL) {
            #pragma unroll
            for (int t = 0; t < 8; ++t) {
                f32x4 acc = {0.f, 0.f, 0.f, 0.f};
                acc = __builtin_amdgcn_mfma_f32_16x16x32_bf16(a[t][0], c00, acc, 0, 0, 0);
                acc = __builtin_amdgcn_mfma_f32_16x16x32_bf16(a[t][1], c01, acc, 0, 0, 0);
                #pragma unroll
                for (int r = 0; r < 4; ++r) ssum[t][r] += __expf(acc[r]);
            }
        } else {
            const bool valid = (v0 * 16 + r16) < VOCAB;
            #pragma unroll
            for (int t = 0; t < 8; ++t) {
                f32x4 acc = {0.f, 0.f, 0.f, 0.f};
                acc = __builtin_amdgcn_mfma_f32_16x16x32_bf16(a[t][0], c00, acc, 0, 0, 0);
                acc = __builtin_amdgcn_mfma_f32_16x16x32_bf16(a[t][1], c01, acc, 0, 0, 0);
                #pragma unroll
                for (int r = 0; r < 4; ++r) ssum[t][r] += valid ? __expf(acc[r]) : 0.f;
            }
        }
        // ---- compute v1 ----
        if (v1 < vt_end) {
            if (v1 < VT_FULL) {
                #pragma unroll
                for (int t = 0; t < 8; ++t) {
                    f32x4 acc = {0.f, 0.f, 0.f, 0.f};
                    acc = __builtin_amdgcn_mfma_f32_16x16x32_bf16(a[t][0], c10, acc, 0, 0, 0);
                    acc = __builtin_amdgcn_mfma_f32_16x16x32_bf16(a[t][1], c11, acc, 0, 0, 0);
                    #pragma unroll
                    for (int r = 0; r < 4; ++r) ssum[t][r] += __expf(acc[r]);
                }
            } else {
                const bool valid = (v1 * 16 + r16) < VOCAB;
                #pragma unroll
                for (int t = 0; t < 8; ++t) {
                    f32x4 acc = {0.f, 0.f, 0.f, 0.f};
                    acc = __builtin_amdgcn_mfma_f32_16x16x32_bf16(a[t][0], c10, acc, 0, 0, 0);
                    acc = __builtin_amdgcn_mfma_f32_16x16x32_bf16(a[t][1], c11, acc, 0, 0, 0);
                    #pragma unroll
                    for (int r = 0; r < 4; ++r) ssum[t][r] += valid ? __expf(acc[r]) : 0.f;
                }
            }
        }
    }
    #undef LOADB

    // reduce exp-sums across the 16 vocab cols (lanes differing in bits 0..3)
    #pragma unroll
    for (int t = 0; t < 8; ++t)
        #pragma unroll
        for (int r = 0; r < 4; ++r) {
            float v = ssum[t][r];
            v += __shfl_xor(v, 1);
            v += __shfl_xor(v, 2);
            v += __shfl_xor(v, 4);
            v += __shfl_xor(v, 8);
            ssum[t][r] = v;
        }

    // cross-wave reduce in LDS -> one value per row per block
    if (r16 == 0) {
        #pragma unroll
        for (int t = 0; t < 8; ++t)
            #pragma unroll
            for (int r = 0; r < 4; ++r)
                s_part[wave][t * 16 + hi * 4 + r] = ssum[t][r];
    }
    __syncthreads();

    if (threadIdx.x < 128) {
        const int i = threadIdx.x;
        const float v = s_part[0][i] + s_part[1][i] + s_part[2][i] + s_part[3][i];
        partials[(size_t)chunk * B_TOT + bg * 128 + i] = v;
    }
}

// ---------------------------------------------------------------------------
// Kernel C: reduce partials, exact fp32 pred logit, emit prob.
// ---------------------------------------------------------------------------
__global__ __launch_bounds__(256) void finalize_kernel(
    const float* __restrict__ Q,
    const float* __restrict__ item_emb,
    const int*   __restrict__ pred,
    const float* __restrict__ partials,
    float*       __restrict__ out)
{
    const int b = blockIdx.x * 256 + threadIdx.x;

    float S = 0.f;
    for (int c = 0; c < NC; ++c)
        S += partials[(size_t)c * B_TOT + b];

    const int pv = pred[b];
    float acc = 0.f;
    const float4* e4 = (const float4*)(item_emb + (long)pv * DIM);
    const float4* q4 = (const float4*)(Q + b * DIM);
    #pragma unroll
    for (int i = 0; i < DIM / 4; ++i) {
        const float4 e = e4[i];
        const float4 q = q4[i];
        acc += e.x*q.x + e.y*q.y + e.z*q.z + e.w*q.w;
    }
    out[b] = __expf(acc) / S;
}

// ---------------------------------------------------------------------------
extern "C" void kernel_launch(void* const* d_in, const int* in_sizes, int n_in,
                              void* d_out, int out_size, void* d_ws, size_t ws_size,
                              hipStream_t stream)
{
    const int*   log_seqs = (const int*)  d_in[0];
    const int*   pred     = (const int*)  d_in[1];
    const float* item_emb = (const float*)d_in[2];
    const float* attn_key = (const float*)d_in[3];
    const float* pos_emb  = (const float*)d_in[4];
    float*       out      = (float*)d_out;

    char* ws = (char*)d_ws;
    __bf16* Eb       = (__bf16*)ws;                                   // 12,800,128 B
    __bf16* Qb       = (__bf16*)(ws + (size_t)VOCAB * DIM * 2);       // 131,072 B
    float*  Qf       = (float*) (ws + (size_t)VOCAB * DIM * 2 + (size_t)B_TOT * DIM * 2);
    float*  partials = (float*) ((char*)Qf + (size_t)B_TOT * DIM * 4); // [128][1024] f32

    pool_kernel<<<B_TOT, 256, 0, stream>>>(log_seqs, item_emb, attn_key, pos_emb, Qf, Qb, Eb);
    logits_mfma<<<NBG * NC, 256, 0, stream>>>(Eb, Qb, partials);
    finalize_kernel<<<B_TOT / 256, 256, 0, stream>>>(Qf, item_emb, pred, partials, out);
}